// Round 1
// baseline (13.021 us; speedup 1.0000x reference)
//
#include <hip/hip_runtime.h>

// out[b,co,h,w] = max over ci of |x[b,ci,h,w] + w[co,ci]|
// B=8, CIN=COUT=64, H=W=56  -> HW=3136, spatial S = B*HW = 25088
//
// Layout: x[(b*64+ci)*3136 + hw], out[(b*64+co)*3136 + hw], w[co*64+ci]
//
// Block: 512 threads = 8 waves. lane (0..63) -> spatial within a 64-chunk
// (3136 % 64 == 0, so b is wave-uniform). wave id (0..7) -> 8 consecutive co.
// Grid: 25088/64 = 392 blocks.

__global__ __launch_bounds__(512) void Conv1x1_53429393162852_kernel(
    const float* __restrict__ x, const float* __restrict__ w,
    float* __restrict__ out) {
  const int lane = threadIdx.x & 63;
  const int wid  = threadIdx.x >> 6;              // 0..7
  const int s    = blockIdx.x * 64 + lane;        // spatial index, < 25088
  const int b    = s / 3136;                      // wave-uniform (chunks aligned)
  const int hw   = s - b * 3136;
  // Force co0 into an SGPR so weight loads become s_load (scalar cache).
  const int co0  = __builtin_amdgcn_readfirstlane(wid * 8);

  const float* xp = x + (size_t)b * 64 * 3136 + hw;
  const float* wp = w + co0 * 64;

  float acc[8];
#pragma unroll
  for (int j = 0; j < 8; ++j) acc[j] = 0.0f;   // |.| >= 0, so 0 is a safe floor

#pragma unroll
  for (int ci = 0; ci < 64; ++ci) {
    const float xv = xp[(size_t)ci * 3136];
#pragma unroll
    for (int j = 0; j < 8; ++j) {
      const float t = xv + wp[j * 64 + ci];     // v_add_f32 v, s, v
      acc[j] = fmaxf(acc[j], fabsf(t));         // v_max_f32 with abs() modifier
    }
  }

  float* op = out + (size_t)b * 64 * 3136 + hw;
#pragma unroll
  for (int j = 0; j < 8; ++j) op[(size_t)(co0 + j) * 3136] = acc[j];
}

extern "C" void kernel_launch(void* const* d_in, const int* in_sizes, int n_in,
                              void* d_out, int out_size, void* d_ws, size_t ws_size,
                              hipStream_t stream) {
  const float* x = (const float*)d_in[0];      // (8, 64, 56, 56) fp32
  const float* w = (const float*)d_in[1];      // (64, 64, 1, 1)  fp32
  float* out = (float*)d_out;                  // (8, 64, 56, 56) fp32

  dim3 grid(392), block(512);
  hipLaunchKernelGGL(Conv1x1_53429393162852_kernel, grid, block, 0, stream,
                     x, w, out);
}